// Round 19
// baseline (246.877 us; speedup 1.0000x reference)
//
#include <hip/hip_runtime.h>
#include <hip/hip_bf16.h>

#define NENT 40000
#define NREL 20
#define DIM 128
#define NBASIS 8
#define TILE 16                // nodes per fused block (32KB G tile -> 4 blocks/CU)
#define PKCAP 512              // LDS-staged packed entries per tile (avg ~256)
#define NBIN (NENT * 2)        // (dst, src-half) bins
#define SCANBLK 313            // ceil(80000/256)
#define SRCHALF (NENT / 2)

typedef __attribute__((ext_vector_type(8))) short sh8;
typedef __attribute__((ext_vector_type(4))) float fx4;
typedef __attribute__((ext_vector_type(2))) float f32x2;

__device__ __forceinline__ short f2bf(float f) {
    union { __hip_bfloat16 h; short s; } u;
    u.h = __float2bfloat16(f);
    return u.s;
}

// ---- fused prelude: tobf | wfrag9(x2) | hist | rel, branched by block range ----
__device__ __forceinline__ void d_tobf(int b, int t, const float* __restrict__ x,
                                       ushort* __restrict__ xb) {
    int i = (b * 256 + t) * 4;
    float4 v = *(const float4*)(x + i);
    ushort4 o;
    o.x = (ushort)f2bf(v.x); o.y = (ushort)f2bf(v.y);
    o.z = (ushort)f2bf(v.z); o.w = (ushort)f2bf(v.w);
    *(ushort4*)(xb + i) = o;
}

__device__ __forceinline__ void d_wfrag9(int b, int tt, const float* __restrict__ basis,
                                         const float* __restrict__ root,
                                         short* __restrict__ Wfb) {
    int t = b * 256 + tt;
    int ks = t / 16384;
    int rem = t & 16383;
    int i = rem >> 7, o = rem & 127;
    float v = (ks < 8) ? basis[ks * 16384 + i * 128 + o] : root[i * 128 + o];
    int c = o >> 4, l15 = o & 15;
    int kk = i >> 5, lhi = (i >> 3) & 3, e = i & 7;
    int lane = l15 + lhi * 16;
    Wfb[(size_t)ks * 16384 + (size_t)(((c * 4 + kk) * 64 + lane) << 3) + e] = f2bf(v);
}

__global__ void k_prep(const float* __restrict__ x, ushort* __restrict__ xb,
                       const float* __restrict__ basis1, const float* __restrict__ root1,
                       short* __restrict__ Wfb1,
                       const float* __restrict__ basis2, const float* __restrict__ root2,
                       short* __restrict__ Wfb2,
                       const int* __restrict__ srcA, const int* __restrict__ dstA,
                       int E, int* __restrict__ hist,
                       const float* __restrict__ rel, const float* __restrict__ wrel,
                       float* __restrict__ outr, int relrows) {
    int b = blockIdx.x, t = threadIdx.x;
    if (b < 5000) {                       // tobf: 40000*128/4/256
        d_tobf(b, t, x, xb);
    } else if (b < 5576) {                // wfrag9 layer 1
        d_wfrag9(b - 5000, t, basis1, root1, Wfb1);
    } else if (b < 6152) {                // wfrag9 layer 2
        d_wfrag9(b - 5576, t, basis2, root2, Wfb2);
    } else if (b < 8652) {                // hist over (dst, src-half) bins
        int e = (b - 6152) * 256 + t;
        if (e < E) {
            int bin = dstA[e] * 2 + (srcA[e] >= SRCHALF ? 1 : 0);
            atomicAdd(&hist[bin], 1);
        }
    } else {                              // rel GEMM: relrows*128
        int idx = (b - 8652) * 256 + t;
        if (idx < relrows * DIM) {
            int j = idx >> 7, o = idx & 127;
            float s = 0.f;
            for (int i = 0; i < DIM; ++i) s += rel[j * DIM + i] * wrel[i * DIM + o];
            outr[idx] = s;
        }
    }
}

// -------- 3-phase parallel scan over NBIN bins --------
__global__ void k_scan1(const int* __restrict__ hist, int* __restrict__ offs,
                        int* __restrict__ bsum) {
    __shared__ int ps[256];
    int t = threadIdx.x;
    int i = blockIdx.x * 256 + t;
    int v = (i < NBIN) ? hist[i] : 0;
    ps[t] = v;
    __syncthreads();
    for (int off = 1; off < 256; off <<= 1) {
        int u = (t >= off) ? ps[t - off] : 0;
        __syncthreads();
        ps[t] += u;
        __syncthreads();
    }
    if (i < NBIN) offs[i] = ps[t] - v;
    if (t == 255) bsum[blockIdx.x] = ps[255];
}

// exclusive scan of SCANBLK block sums (313), chunked 2/thread
__global__ void k_scan2(int* __restrict__ bsum) {
    __shared__ int ps[256];
    int t = threadIdx.x;
    const int chunk = (SCANBLK + 255) / 256;   // 2
    int lo = t * chunk, hi = min(SCANBLK, lo + chunk);
    int s = 0;
    for (int i = lo; i < hi; ++i) s += bsum[i];
    ps[t] = s;
    __syncthreads();
    for (int off = 1; off < 256; off <<= 1) {
        int u = (t >= off) ? ps[t - off] : 0;
        __syncthreads();
        ps[t] += u;
        __syncthreads();
    }
    int run = (t == 0) ? 0 : ps[t - 1];
    for (int i = lo; i < hi; ++i) {
        int v = bsum[i];
        bsum[i] = run;
        run += v;
    }
}

__global__ void k_scan3(int* __restrict__ offs, int* __restrict__ cursor,
                        const int* __restrict__ bsum, int E) {
    int i = blockIdx.x * 256 + threadIdx.x;
    if (i < NBIN) {
        int o = offs[i] + bsum[blockIdx.x];
        offs[i] = o;
        cursor[i] = o;
    }
    if (i == 0) offs[NBIN] = E;
}

// counting-sort by (dst, src-half): packed = src | et<<16
__global__ void k_scatter(const int* __restrict__ et, const int* __restrict__ srcA,
                          const int* __restrict__ dstA, int E,
                          int* __restrict__ cursor, unsigned* __restrict__ packed) {
    int e = blockIdx.x * 256 + threadIdx.x;
    if (e >= E) return;
    int bin = dstA[e] * 2 + (srcA[e] >= SRCHALF ? 1 : 0);
    int pos = atomicAdd(&cursor[bin], 1);
    packed[pos] = (unsigned)srcA[e] | ((unsigned)et[e] << 16);
}

// pinned async load, saddr form: scalar 64-bit base + per-lane 32-bit offset
#define GLDS(dst, voff, sbase)                                             \
    asm volatile("global_load_dword %0, %1, %2"                            \
                 : "=v"(dst) : "v"(voff), "s"(sbase))

#define WAITV(N)                                                           \
    do {                                                                   \
        asm volatile("s_waitcnt vmcnt(" #N ")" ::: "memory");              \
        __builtin_amdgcn_sched_barrier(0);                                 \
    } while (0)

// packed 2-wide FMA core
#define FMA8(AV, CWA, CWB, XP)                                             \
    AV[0] += (f32x2){(CWA).x, (CWA).x} * (XP);                             \
    AV[1] += (f32x2){(CWA).y, (CWA).y} * (XP);                             \
    AV[2] += (f32x2){(CWA).z, (CWA).z} * (XP);                             \
    AV[3] += (f32x2){(CWA).w, (CWA).w} * (XP);                             \
    AV[4] += (f32x2){(CWB).x, (CWB).x} * (XP);                             \
    AV[5] += (f32x2){(CWB).y, (CWB).y} * (XP);                             \
    AV[6] += (f32x2){(CWB).z, (CWB).z} * (XP);                             \
    AV[7] += (f32x2){(CWB).w, (CWB).w} * (XP);

// Fused RGCN layer: block = 16 dst nodes, 8 waves, wave = 2 nodes.
// Phase 1: gather in TWO device-wide src-half phases (edges sorted by
//   (dst, src-half)); per-node accumulators persist across phases, so the
//   instantaneous row working set is 5MB (fits per-XCD L2 better than 10MB).
//   Pipeline per segment = R18's proven scalar-metadata + saddr-pinned
//   8-deep ping-pong with counted vmcnt.
// Phase 2: C[16x128] = [G_lds(1024) | x(128)] @ Wfb + bias via MFMA.
__global__ __launch_bounds__(512) void k_fused(
    const ushort* __restrict__ xb, const unsigned* __restrict__ packed,
    const int* __restrict__ offs, const float* __restrict__ comp,
    const short* __restrict__ Wfb, const float* __restrict__ bias,
    ushort* __restrict__ outbf, float* __restrict__ outf, int act) {
    __shared__ __align__(16) ushort Gl[TILE * 1024];   // 32KB
    __shared__ __align__(16) unsigned pkl[PKCAP];      // 2KB

    int t = threadIdx.x;
    int lane = t & 63, wid = t >> 6;
    unsigned lane4 = (unsigned)(lane * 4);

    int tile0 = blockIdx.x * TILE;
    int bin0 = tile0 * 2;
    int base = offs[bin0];
    int totE = offs[bin0 + TILE * 2] - base;
    for (int i = t; i < totE && i < PKCAP; i += 512) pkl[i] = packed[base + i];
    __syncthreads();

    // node/segment offsets for this wave's 2 nodes (4 segments)
    int n0b = (tile0 + wid * 2) * 2;
    int o0 = offs[n0b], o1 = offs[n0b + 1], o2 = offs[n0b + 2],
        o3 = offs[n0b + 3], o4 = offs[n0b + 4];
    int cnt0 = o2 - o0, cnt1 = o4 - o2;   // per-node totals (for mean)

    f32x2 av0[NBASIS], av1[NBASIS];
#pragma unroll
    for (int b = 0; b < NBASIS; ++b) { av0[b] = (f32x2){0.f, 0.f}; av1[b] = (f32x2){0.f, 0.f}; }

    bool fast = (totE <= PKCAP);

    auto seg = [&](int begg, int cnt, f32x2 (&av)[NBASIS]) {
        if (cnt <= 0) return;
        int begl = begg - base;
        if (fast) {
            int sbA[8], seA[8], sbB[8], seB[8];
            unsigned rA[8], rB[8];

            auto ldp = [&](int i0, int (&sb)[8], int (&se)[8]) {
#pragma unroll
                for (int u = 0; u < 8; ++u) {
                    int i = i0 + u;
                    int li = begl + (i < cnt ? i : 0);   // clamp: L1-hot row
                    unsigned p = __builtin_amdgcn_readfirstlane(pkl[li]);
                    sb[u] = (int)(p & 0xFFFFu) * 256;    // scalar byte offset
                    se[u] = (int)(p >> 16);
                }
            };
            auto issue = [&](const int (&sb)[8], unsigned (&r)[8]) {
#pragma unroll
                for (int u = 0; u < 8; ++u) {
                    const char* bp = (const char*)xb + sb[u];   // uniform base
                    GLDS(r[u], lane4, bp);
                }
            };
            auto proc = [&](int i0, const int (&se)[8], const unsigned (&r)[8]) {
#pragma unroll
                for (int u = 0; u < 8; ++u) {
                    if (i0 + u < cnt) {      // wave-uniform
                        const float4* cp = (const float4*)(comp + se[u] * NBASIS);
                        float4 cwa = cp[0];  // scalar-cache loads
                        float4 cwb = cp[1];
                        f32x2 xp = {__uint_as_float(r[u] << 16),
                                    __uint_as_float(r[u] & 0xFFFF0000u)};
                        FMA8(av, cwa, cwb, xp)
                    }
                }
            };

            ldp(0, sbA, seA); issue(sbA, rA);            // 8 outstanding
            int i0 = 0;
            while (i0 < cnt) {
                ldp(i0 + 8, sbB, seB); issue(sbB, rB);   // 16 outstanding
                WAITV(8);                                // batch A landed
                proc(i0, seA, rA);
                i0 += 8;
                if (i0 >= cnt) break;
                ldp(i0 + 8, sbA, seA); issue(sbA, rA);
                WAITV(8);                                // batch B landed
                proc(i0, seB, rB);
                i0 += 8;
            }
            asm volatile("s_waitcnt vmcnt(0)" ::: "memory");  // drain speculative
            __builtin_amdgcn_sched_barrier(0);
        } else {
            // slow fallback (tile overflows PKCAP): depth-2 scalar pipeline
            const unsigned* xrow = (const unsigned*)xb + lane;
            unsigned pA = packed[begg], pB = 0, rA = xrow[(size_t)(pA & 0xFFFFu) * 64];
            if (cnt > 1) pB = packed[begg + 1];
            for (int i = 0; i < cnt; ++i) {
                unsigned pC = (i + 2 < cnt) ? packed[begg + i + 2] : 0u;
                unsigned rB = xrow[(size_t)(pB & 0xFFFFu) * 64];
                int et = pA >> 16;
                const float4* cp = (const float4*)(comp + et * NBASIS);
                float4 cwa = cp[0];
                float4 cwb = cp[1];
                f32x2 xp = {__uint_as_float(rA << 16),
                            __uint_as_float(rA & 0xFFFF0000u)};
                FMA8(av, cwa, cwb, xp)
                pA = pB; pB = pC; rA = rB;
            }
        }
    };

    // device-wide phase 0: src-lo segments; phase 1: src-hi segments
    seg(o0, o1 - o0, av0);
    seg(o2, o3 - o2, av1);
    seg(o1, o2 - o1, av0);
    seg(o3, o4 - o3, av1);

    // per-node mean + LDS G write (XOR bank swizzle)
#define WRITEG(AV, SUB, CN)                                                \
    do {                                                                   \
        float inv = 1.f / (float)((CN) < 1 ? 1 : (CN));                    \
        int row = wid * 2 + (SUB);                                         \
        _Pragma("unroll")                                                  \
        for (int b = 0; b < NBASIS; ++b) {                                 \
            unsigned lo = (unsigned)(ushort)f2bf(AV[b][0] * inv);          \
            unsigned hi = (unsigned)(ushort)f2bf(AV[b][1] * inv);          \
            unsigned byteoff = (unsigned)(row * 2048 + b * 256 + lane * 4);\
            byteoff ^= (unsigned)((row & 7) << 4);                         \
            *(unsigned*)((char*)Gl + byteoff) = lo | (hi << 16);           \
        }                                                                  \
    } while (0)

    WRITEG(av0, 0, cnt0);
    WRITEG(av1, 1, cnt1);
#undef WRITEG
    __syncthreads();

    // ---- phase 2: MFMA GEMM (wave = one 16-col group x all 16 rows) ----
    int l15 = lane & 15, lhi = lane >> 4;
    int c = wid;                              // col-group 0..7

    fx4 acc0 = (fx4){0.f, 0.f, 0.f, 0.f};    // rows 0..15

    const sh8* W8 = (const sh8*)Wfb;

#pragma unroll
    for (int ks = 0; ks < 9; ++ks) {
        sh8 a0f[4];
        if (ks < 8) {
#pragma unroll
            for (int kk = 0; kk < 4; ++kk) {
                int ar0 = l15;
                unsigned bo0 = (unsigned)(ar0 * 2048 + ks * 256 + kk * 64 + lhi * 16);
                bo0 ^= (unsigned)((ar0 & 7) << 4);
                a0f[kk] = *(const sh8*)((const char*)Gl + bo0);
            }
        } else {
#pragma unroll
            for (int kk = 0; kk < 4; ++kk) {
                a0f[kk] = *(const sh8*)(xb + (size_t)(tile0 + l15) * 128 + lhi * 8 + kk * 32);
            }
        }
#pragma unroll
        for (int kk = 0; kk < 4; ++kk) {
            sh8 b = W8[(size_t)ks * 2048 + (size_t)((c * 4 + kk) * 64 + lane)];
            acc0 = __builtin_amdgcn_mfma_f32_16x16x32_bf16(a0f[kk], b, acc0, 0, 0, 0);
        }
    }

    // bias + act + store
    int col = c * 16 + l15;
    float bv = bias[col];
    int orow0 = tile0 + lhi * 4;
#pragma unroll
    for (int j = 0; j < 4; ++j) {
        float v = acc0[j] + bv;
        if (act) {
            v = tanhf(v);
            outbf[(size_t)(orow0 + j) * 128 + col] = (ushort)f2bf(v);
        } else {
            outf[(size_t)(orow0 + j) * 128 + col] = v;
        }
    }
}

extern "C" void kernel_launch(void* const* d_in, const int* in_sizes, int n_in,
                              void* d_out, int out_size, void* d_ws, size_t ws_size,
                              hipStream_t stream) {
    const int* edge_index = (const int*)d_in[0];
    const int* edge_type  = (const int*)d_in[1];
    const float* init_embed = (const float*)d_in[2];
    const float* init_rel   = (const float*)d_in[3];
    const float* w_rel      = (const float*)d_in[4];
    const float* comp1  = (const float*)d_in[5];
    const float* basis1 = (const float*)d_in[6];
    const float* root1  = (const float*)d_in[7];
    const float* bias1  = (const float*)d_in[8];
    const float* comp2  = (const float*)d_in[9];
    const float* basis2 = (const float*)d_in[10];
    const float* root2  = (const float*)d_in[11];
    const float* bias2  = (const float*)d_in[12];

    int E = in_sizes[1];
    const int* src = edge_index;
    const int* dst = edge_index + E;
    int relrows = in_sizes[3] / DIM;   // 40

    // workspace layout (16B-aligned regions)
    short* Wfb1 = (short*)d_ws;                          // 9*16384 shorts
    short* Wfb2 = Wfb1 + (size_t)9 * 16384;
    ushort* xb  = (ushort*)(Wfb2 + (size_t)9 * 16384);   // 40000*128 bf16
    ushort* hb  = xb + (size_t)NENT * DIM;               // 40000*128 bf16
    int* hist   = (int*)(hb + (size_t)NENT * DIM);       // 80000 (pad 80004)
    int* offs   = hist + 80004;                          // 80001 (pad 80004)
    int* cursor = offs + 80004;                          // 80000 (pad 80004)
    int* bsum   = cursor + 80004;                        // 313 (pad 320)
    unsigned* packed = (unsigned*)(bsum + 320);          // E

    float* outx = (float*)d_out;
    float* outr = outx + (size_t)NENT * DIM;

    hipMemsetAsync(hist, 0, NBIN * sizeof(int), stream);

    int relblocks = (relrows * DIM + 255) / 256;         // 20 for 40 rows
    k_prep<<<8652 + relblocks, 256, 0, stream>>>(
        init_embed, xb, basis1, root1, Wfb1, basis2, root2, Wfb2,
        src, dst, E, hist, init_rel, w_rel, outr, relrows);
    k_scan1<<<SCANBLK, 256, 0, stream>>>(hist, offs, bsum);
    k_scan2<<<1, 256, 0, stream>>>(bsum);
    k_scan3<<<SCANBLK, 256, 0, stream>>>(offs, cursor, bsum, E);
    k_scatter<<<(E + 255) / 256, 256, 0, stream>>>(edge_type, src, dst, E, cursor, packed);

    // layer 1: hb = bf16(tanh(gather@W~1 + x@root1 + bias1))
    k_fused<<<NENT / TILE, 512, 0, stream>>>(xb, packed, offs, comp1, Wfb1, bias1,
                                             hb, outx, 1);
    // layer 2: out = gather@W~2 + h@root2 + bias2 (f32 to d_out)
    k_fused<<<NENT / TILE, 512, 0, stream>>>(hb, packed, offs, comp2, Wfb2, bias2,
                                             hb, outx, 0);
}

// Round 20
// 222.339 us; speedup vs baseline: 1.1104x; 1.1104x over previous
//
#include <hip/hip_runtime.h>
#include <hip/hip_bf16.h>

#define NENT 40000
#define NREL 20
#define DIM 128
#define NBASIS 8
#define TILE 16                // nodes per fused block (32KB G tile -> 4 blocks/CU)
#define PKCAP 512              // LDS-staged packed entries per tile (avg ~256)
#define SCANBLK 157            // ceil(40000/256)

typedef __attribute__((ext_vector_type(8))) short sh8;
typedef __attribute__((ext_vector_type(4))) float fx4;
typedef __attribute__((ext_vector_type(2))) float f32x2;

__device__ __forceinline__ short f2bf(float f) {
    union { __hip_bfloat16 h; short s; } u;
    u.h = __float2bfloat16(f);
    return u.s;
}

// ---- fused prelude: tobf | wfrag9(x2) | hist | rel, branched by block range ----
__device__ __forceinline__ void d_tobf(int b, int t, const float* __restrict__ x,
                                       ushort* __restrict__ xb) {
    int i = (b * 256 + t) * 4;
    float4 v = *(const float4*)(x + i);
    ushort4 o;
    o.x = (ushort)f2bf(v.x); o.y = (ushort)f2bf(v.y);
    o.z = (ushort)f2bf(v.z); o.w = (ushort)f2bf(v.w);
    *(ushort4*)(xb + i) = o;
}

__device__ __forceinline__ void d_wfrag9(int b, int tt, const float* __restrict__ basis,
                                         const float* __restrict__ root,
                                         short* __restrict__ Wfb) {
    int t = b * 256 + tt;
    int ks = t / 16384;
    int rem = t & 16383;
    int i = rem >> 7, o = rem & 127;
    float v = (ks < 8) ? basis[ks * 16384 + i * 128 + o] : root[i * 128 + o];
    int c = o >> 4, l15 = o & 15;
    int kk = i >> 5, lhi = (i >> 3) & 3, e = i & 7;
    int lane = l15 + lhi * 16;
    Wfb[(size_t)ks * 16384 + (size_t)(((c * 4 + kk) * 64 + lane) << 3) + e] = f2bf(v);
}

__global__ void k_prep(const float* __restrict__ x, ushort* __restrict__ xb,
                       const float* __restrict__ basis1, const float* __restrict__ root1,
                       short* __restrict__ Wfb1,
                       const float* __restrict__ basis2, const float* __restrict__ root2,
                       short* __restrict__ Wfb2,
                       const int* __restrict__ dst, int E, int* __restrict__ hist,
                       const float* __restrict__ rel, const float* __restrict__ wrel,
                       float* __restrict__ outr, int relrows) {
    int b = blockIdx.x, t = threadIdx.x;
    if (b < 5000) {                       // tobf: 40000*128/4/256
        d_tobf(b, t, x, xb);
    } else if (b < 5576) {                // wfrag9 layer 1
        d_wfrag9(b - 5000, t, basis1, root1, Wfb1);
    } else if (b < 6152) {                // wfrag9 layer 2
        d_wfrag9(b - 5576, t, basis2, root2, Wfb2);
    } else if (b < 8652) {                // hist: 640000/256
        int e = (b - 6152) * 256 + t;
        if (e < E) atomicAdd(&hist[dst[e]], 1);
    } else {                              // rel GEMM: relrows*128
        int idx = (b - 8652) * 256 + t;
        if (idx < relrows * DIM) {
            int j = idx >> 7, o = idx & 127;
            float s = 0.f;
            for (int i = 0; i < DIM; ++i) s += rel[j * DIM + i] * wrel[i * DIM + o];
            outr[idx] = s;
        }
    }
}

// -------- 3-phase parallel scan over NENT bins --------
__global__ void k_scan1(const int* __restrict__ hist, int* __restrict__ offs,
                        int* __restrict__ bsum) {
    __shared__ int ps[256];
    int t = threadIdx.x;
    int i = blockIdx.x * 256 + t;
    int v = (i < NENT) ? hist[i] : 0;
    ps[t] = v;
    __syncthreads();
    for (int off = 1; off < 256; off <<= 1) {
        int u = (t >= off) ? ps[t - off] : 0;
        __syncthreads();
        ps[t] += u;
        __syncthreads();
    }
    if (i < NENT) offs[i] = ps[t] - v;
    if (t == 255) bsum[blockIdx.x] = ps[255];
}

__global__ void k_scan2(int* __restrict__ bsum) {
    __shared__ int ps[256];
    int t = threadIdx.x;
    int v = (t < SCANBLK) ? bsum[t] : 0;
    ps[t] = v;
    __syncthreads();
    for (int off = 1; off < 256; off <<= 1) {
        int u = (t >= off) ? ps[t - off] : 0;
        __syncthreads();
        ps[t] += u;
        __syncthreads();
    }
    if (t < SCANBLK) bsum[t] = ps[t] - v;
}

__global__ void k_scan3(int* __restrict__ offs, int* __restrict__ cursor,
                        const int* __restrict__ bsum, int E) {
    int i = blockIdx.x * 256 + threadIdx.x;
    if (i < NENT) {
        int o = offs[i] + bsum[blockIdx.x];
        offs[i] = o;
        cursor[i] = o;
    }
    if (i == 0) offs[NENT] = E;
}

// counting-sort by dst: packed = src | et<<16
__global__ void k_scatter(const int* __restrict__ et, const int* __restrict__ srcA,
                          const int* __restrict__ dstA, int E,
                          int* __restrict__ cursor, unsigned* __restrict__ packed) {
    int e = blockIdx.x * 256 + threadIdx.x;
    if (e >= E) return;
    int pos = atomicAdd(&cursor[dstA[e]], 1);
    packed[pos] = (unsigned)srcA[e] | ((unsigned)et[e] << 16);
}

// pinned async load, saddr form: scalar 64-bit base + per-lane 32-bit offset
#define GLDS(dst, voff, sbase)                                             \
    asm volatile("global_load_dword %0, %1, %2"                            \
                 : "=v"(dst) : "v"(voff), "s"(sbase))

#define WAITV(N)                                                           \
    do {                                                                   \
        asm volatile("s_waitcnt vmcnt(" #N ")" ::: "memory");              \
        __builtin_amdgcn_sched_barrier(0);                                 \
    } while (0)

// packed 2-wide FMA core: av[b] = {lo-col acc, hi-col acc}; 8 v_pk_fma_f32
#define FMA8(AV, CWA, CWB, XP)                                             \
    AV[0] += (f32x2){(CWA).x, (CWA).x} * (XP);                             \
    AV[1] += (f32x2){(CWA).y, (CWA).y} * (XP);                             \
    AV[2] += (f32x2){(CWA).z, (CWA).z} * (XP);                             \
    AV[3] += (f32x2){(CWA).w, (CWA).w} * (XP);                             \
    AV[4] += (f32x2){(CWB).x, (CWB).x} * (XP);                             \
    AV[5] += (f32x2){(CWB).y, (CWB).y} * (XP);                             \
    AV[6] += (f32x2){(CWB).z, (CWB).z} * (XP);                             \
    AV[7] += (f32x2){(CWB).w, (CWB).w} * (XP);

// Fused RGCN layer: block = 16 dst nodes, 8 waves, wave = 2 nodes.
// Phase 1 (R17 structure): scalar-pipe metadata, saddr-pinned 8-deep
//   ping-pong row loads, counted vmcnt; FMA core f32x2 (v_pk_fma_f32).
// Phase 2: C[16x128] = [G_lds(1024) | x(128)] @ Wfb + bias via MFMA.
__global__ __launch_bounds__(512) void k_fused(
    const ushort* __restrict__ xb, const unsigned* __restrict__ packed,
    const int* __restrict__ offs, const float* __restrict__ comp,
    const short* __restrict__ Wfb, const float* __restrict__ bias,
    ushort* __restrict__ outbf, float* __restrict__ outf, int act) {
    __shared__ __align__(16) ushort Gl[TILE * 1024];   // 32KB
    __shared__ __align__(16) unsigned pkl[PKCAP];      // 2KB

    int t = threadIdx.x;
    int lane = t & 63, wid = t >> 6;
    unsigned lane4 = (unsigned)(lane * 4);

    int tile0 = blockIdx.x * TILE;
    int base = offs[tile0];
    int totE = offs[tile0 + TILE] - base;
    for (int i = t; i < totE && i < PKCAP; i += 512) pkl[i] = packed[base + i];
    __syncthreads();

    // ---- phase 1: gather (2 nodes per wave, scalar-metadata pipeline) ----
    bool fast = (totE <= PKCAP);
    for (int sub = 0; sub < 2; ++sub) {
        int row = wid * 2 + sub;             // 0..15
        int n = tile0 + row;
        int begg = offs[n];
        int cnt = offs[n + 1] - begg;
        int begl = begg - base;

        f32x2 av[NBASIS];
#pragma unroll
        for (int b = 0; b < NBASIS; ++b) av[b] = (f32x2){0.f, 0.f};

        if (cnt > 0 && fast) {
            int sbA[8], seA[8], sbB[8], seB[8];
            unsigned rA[8], rB[8];

            auto ldp = [&](int i0, int (&sb)[8], int (&se)[8]) {
#pragma unroll
                for (int u = 0; u < 8; ++u) {
                    int i = i0 + u;
                    int li = begl + (i < cnt ? i : 0);   // clamp: L1-hot row
                    unsigned p = __builtin_amdgcn_readfirstlane(pkl[li]);
                    sb[u] = (int)(p & 0xFFFFu) * 256;    // scalar byte offset
                    se[u] = (int)(p >> 16);
                }
            };
            auto issue = [&](const int (&sb)[8], unsigned (&r)[8]) {
#pragma unroll
                for (int u = 0; u < 8; ++u) {
                    const char* bp = (const char*)xb + sb[u];   // uniform base
                    GLDS(r[u], lane4, bp);
                }
            };
            auto proc = [&](int i0, const int (&se)[8], const unsigned (&r)[8]) {
#pragma unroll
                for (int u = 0; u < 8; ++u) {
                    if (i0 + u < cnt) {      // wave-uniform
                        const float4* cp = (const float4*)(comp + se[u] * NBASIS);
                        float4 cwa = cp[0];  // scalar-cache loads
                        float4 cwb = cp[1];
                        f32x2 xp = {__uint_as_float(r[u] << 16),
                                    __uint_as_float(r[u] & 0xFFFF0000u)};
                        FMA8(av, cwa, cwb, xp)
                    }
                }
            };

            ldp(0, sbA, seA); issue(sbA, rA);            // 8 outstanding
            int i0 = 0;
            while (i0 < cnt) {
                ldp(i0 + 8, sbB, seB); issue(sbB, rB);   // 16 outstanding
                WAITV(8);                                // batch A landed
                proc(i0, seA, rA);
                i0 += 8;
                if (i0 >= cnt) break;
                ldp(i0 + 8, sbA, seA); issue(sbA, rA);
                WAITV(8);                                // batch B landed
                proc(i0, seB, rB);
                i0 += 8;
            }
            asm volatile("s_waitcnt vmcnt(0)" ::: "memory");  // drain speculative
            __builtin_amdgcn_sched_barrier(0);
        } else if (cnt > 0) {
            // slow fallback (tile overflows PKCAP): depth-2 scalar pipeline
            const unsigned* xrow = (const unsigned*)xb + lane;
            unsigned pA = packed[begg], pB = 0, rA = xrow[(size_t)(pA & 0xFFFFu) * 64];
            if (cnt > 1) pB = packed[begg + 1];
            for (int i = 0; i < cnt; ++i) {
                unsigned pC = (i + 2 < cnt) ? packed[begg + i + 2] : 0u;
                unsigned rB = xrow[(size_t)(pB & 0xFFFFu) * 64];
                int et = pA >> 16;
                const float4* cp = (const float4*)(comp + et * NBASIS);
                float4 cwa = cp[0];
                float4 cwb = cp[1];
                f32x2 xp = {__uint_as_float(rA << 16),
                            __uint_as_float(rA & 0xFFFF0000u)};
                FMA8(av, cwa, cwb, xp)
                pA = pB; pB = pC; rA = rB;
            }
        }

        float inv = 1.f / (float)(cnt < 1 ? 1 : cnt);
#pragma unroll
        for (int b = 0; b < NBASIS; ++b) {
            unsigned lo = (unsigned)(ushort)f2bf(av[b][0] * inv);
            unsigned hi = (unsigned)(ushort)f2bf(av[b][1] * inv);
            unsigned byteoff = (unsigned)(row * 2048 + b * 256 + lane * 4);
            byteoff ^= (unsigned)((row & 7) << 4);   // bank swizzle
            *(unsigned*)((char*)Gl + byteoff) = lo | (hi << 16);
        }
    }
    __syncthreads();

    // ---- phase 2: MFMA GEMM (wave = one 16-col group x all 16 rows) ----
    int l15 = lane & 15, lhi = lane >> 4;
    int c = wid;                              // col-group 0..7

    fx4 acc0 = (fx4){0.f, 0.f, 0.f, 0.f};    // rows 0..15

    const sh8* W8 = (const sh8*)Wfb;

#pragma unroll
    for (int ks = 0; ks < 9; ++ks) {
        sh8 a0f[4];
        if (ks < 8) {
#pragma unroll
            for (int kk = 0; kk < 4; ++kk) {
                int ar0 = l15;
                unsigned bo0 = (unsigned)(ar0 * 2048 + ks * 256 + kk * 64 + lhi * 16);
                bo0 ^= (unsigned)((ar0 & 7) << 4);
                a0f[kk] = *(const sh8*)((const char*)Gl + bo0);
            }
        } else {
#pragma unroll
            for (int kk = 0; kk < 4; ++kk) {
                a0f[kk] = *(const sh8*)(xb + (size_t)(tile0 + l15) * 128 + lhi * 8 + kk * 32);
            }
        }
#pragma unroll
        for (int kk = 0; kk < 4; ++kk) {
            sh8 b = W8[(size_t)ks * 2048 + (size_t)((c * 4 + kk) * 64 + lane)];
            acc0 = __builtin_amdgcn_mfma_f32_16x16x32_bf16(a0f[kk], b, acc0, 0, 0, 0);
        }
    }

    // bias + act + store
    int col = c * 16 + l15;
    float bv = bias[col];
    int orow0 = tile0 + lhi * 4;
#pragma unroll
    for (int j = 0; j < 4; ++j) {
        float v = acc0[j] + bv;
        if (act) {
            v = tanhf(v);
            outbf[(size_t)(orow0 + j) * 128 + col] = (ushort)f2bf(v);
        } else {
            outf[(size_t)(orow0 + j) * 128 + col] = v;
        }
    }
}

extern "C" void kernel_launch(void* const* d_in, const int* in_sizes, int n_in,
                              void* d_out, int out_size, void* d_ws, size_t ws_size,
                              hipStream_t stream) {
    const int* edge_index = (const int*)d_in[0];
    const int* edge_type  = (const int*)d_in[1];
    const float* init_embed = (const float*)d_in[2];
    const float* init_rel   = (const float*)d_in[3];
    const float* w_rel      = (const float*)d_in[4];
    const float* comp1  = (const float*)d_in[5];
    const float* basis1 = (const float*)d_in[6];
    const float* root1  = (const float*)d_in[7];
    const float* bias1  = (const float*)d_in[8];
    const float* comp2  = (const float*)d_in[9];
    const float* basis2 = (const float*)d_in[10];
    const float* root2  = (const float*)d_in[11];
    const float* bias2  = (const float*)d_in[12];

    int E = in_sizes[1];
    const int* src = edge_index;
    const int* dst = edge_index + E;
    int relrows = in_sizes[3] / DIM;   // 40

    // workspace layout (16B-aligned regions)
    short* Wfb1 = (short*)d_ws;                          // 9*16384 shorts
    short* Wfb2 = Wfb1 + (size_t)9 * 16384;
    ushort* xb  = (ushort*)(Wfb2 + (size_t)9 * 16384);   // 40000*128 bf16
    ushort* hb  = xb + (size_t)NENT * DIM;               // 40000*128 bf16
    int* hist   = (int*)(hb + (size_t)NENT * DIM);       // 40000 (pad 40004)
    int* offs   = hist + 40004;
    int* cursor = offs + 40004;
    int* bsum   = cursor + 40004;                        // 157 (pad 160)
    unsigned* packed = (unsigned*)(bsum + 160);          // E

    float* outx = (float*)d_out;
    float* outr = outx + (size_t)NENT * DIM;

    hipMemsetAsync(hist, 0, NENT * sizeof(int), stream);

    int relblocks = (relrows * DIM + 255) / 256;         // 20 for 40 rows
    k_prep<<<8652 + relblocks, 256, 0, stream>>>(
        init_embed, xb, basis1, root1, Wfb1, basis2, root2, Wfb2,
        dst, E, hist, init_rel, w_rel, outr, relrows);
    k_scan1<<<SCANBLK, 256, 0, stream>>>(hist, offs, bsum);
    k_scan2<<<1, 256, 0, stream>>>(bsum);
    k_scan3<<<SCANBLK, 256, 0, stream>>>(offs, cursor, bsum, E);
    k_scatter<<<(E + 255) / 256, 256, 0, stream>>>(edge_type, src, dst, E, cursor, packed);

    // layer 1: hb = bf16(tanh(gather@W~1 + x@root1 + bias1))
    k_fused<<<NENT / TILE, 512, 0, stream>>>(xb, packed, offs, comp1, Wfb1, bias1,
                                             hb, outx, 1);
    // layer 2: out = gather@W~2 + h@root2 + bias2 (f32 to d_out)
    k_fused<<<NENT / TILE, 512, 0, stream>>>(hb, packed, offs, comp2, Wfb2, bias2,
                                             hb, outx, 0);
}